// Round 3
// baseline (1238.808 us; speedup 1.0000x reference)
//
#include <hip/hip_runtime.h>
#include <hip/hip_bf16.h>

// AUGRU dynamic RNN:  B=1024 batch rows, T=512 steps, D=128.
// 64 blocks x 512 threads (8 waves); block owns 16 batch rows for all T.
// Round-3 change vs verified 630us kernel: x A-fragments no longer staged
// through LDS. Each lane loads its own A-slice X[b0+lm][t][ks*32+q*8..+8]
// directly from global (f32), one step ahead, into registers; converts to
// bf16 frags at step top. All 8 waves read identical addresses -> L1-hit
// broadcast. Deletes 4 of 12 ds_read_b128/thread/step (-33% of the LDS
// b128 broadcast traffic; LDS pipe measured ~75% busy), xb staging writes,
// and 8.7 KB LDS. barrier_lds (lgkm-only, round-2) is kept and is now
// REQUIRED: __syncthreads would drain the in-flight x prefetch each step.
// launch_bounds relaxed to (512,1): +~48 VGPR for prefetch regs; occupancy
// is structurally 1 block/CU (64 blocks on 64 CUs).

#define Bn 1024
#define Tn 512
#define Dn 128

typedef __attribute__((ext_vector_type(8))) short short8;   // 8 bf16 (4 VGPR)
typedef __attribute__((ext_vector_type(4))) float f32x4;

#define HS 132   // f32 LDS row stride (floats)  : 16x128 + pad
#define BS 136   // bf16 LDS row stride (shorts) : 272 B = 17*16B

__device__ __forceinline__ short f2bf(float f) {
    __hip_bfloat16 h = __float2bfloat16(f);   // RNE
    return __builtin_bit_cast(short, h);
}
__device__ __forceinline__ float sigmoidf_(float x) {
    float e = __expf(-x);
    return __builtin_amdgcn_rcpf(1.0f + e);
}
__device__ __forceinline__ float tanhf_(float x) {
    float e = __expf(-2.0f * x);
    return 2.0f * __builtin_amdgcn_rcpf(1.0f + e) - 1.0f;
}

// LDS-only barrier: order LDS ops across waves WITHOUT draining vmcnt
// (the x prefetch loads keep flying across both barriers).
__device__ __forceinline__ void barrier_lds() {
    __builtin_amdgcn_sched_barrier(0);
    asm volatile("s_waitcnt lgkmcnt(0)" ::: "memory");
    __builtin_amdgcn_s_barrier();
    __builtin_amdgcn_sched_barrier(0);
}

__launch_bounds__(512, 1)
__global__ void augru_kernel(const float* __restrict__ X,    // [B,T,D]
                             const float* __restrict__ ATT,  // [B,T,1]
                             const float* __restrict__ GK,   // [256,256]
                             const float* __restrict__ GB,   // [256]
                             const float* __restrict__ CK,   // [256,128]
                             const float* __restrict__ CB,   // [128]
                             const int*   __restrict__ SL,   // [B,1]
                             float* __restrict__ OUT) {      // [B,T,D]
    __shared__ short hb [16 * BS];      // h  (bf16 mirror, A-frag source)
    __shared__ short rhb[16 * BS];      // r*h (bf16, A-frag source)
    __shared__ float hf [16 * HS];      // master h (f32)
    __shared__ float ub [16 * HS];      // u' = (1-a)*u (f32)
    __shared__ float abuf[2][16];
    __shared__ int   lenbuf[16];

    const int tid  = threadIdx.x;
    const int wid  = tid >> 6;          // 0..7
    const int lane = tid & 63;
    const int lm   = lane & 15;         // MFMA m / n / col index
    const int q    = lane >> 4;         // quad
    const int b0   = blockIdx.x * 16;

    // ---------- preload weight B-frags (B[k][n]: n=lane&15, k=q*8+j) ----------
    short8 fgx[2][4], fgh[2][4], fcx[4], fch[4];
    const int gcolb = 32 * wid + lm;     // gate col base for this wave
    const int ccol  = 16 * wid + lm;     // cand col for this wave
#pragma unroll
    for (int ns = 0; ns < 2; ++ns) {
        const int col = gcolb + 16 * ns;
#pragma unroll
        for (int ks = 0; ks < 4; ++ks) {
            short8 vx, vh;
#pragma unroll
            for (int j = 0; j < 8; ++j) {
                const int k = ks * 32 + q * 8 + j;
                vx[j] = f2bf(GK[k * 256 + col]);           // x-part rows 0..127
                vh[j] = f2bf(GK[(128 + k) * 256 + col]);   // h-part rows 128..255
            }
            fgx[ns][ks] = vx; fgh[ns][ks] = vh;
        }
    }
#pragma unroll
    for (int ks = 0; ks < 4; ++ks) {
        short8 vx, vh;
#pragma unroll
        for (int j = 0; j < 8; ++j) {
            const int k = ks * 32 + q * 8 + j;
            vx[j] = f2bf(CK[k * 128 + ccol]);
            vh[j] = f2bf(CK[(128 + k) * 128 + ccol]);
        }
        fcx[ks] = vx; fch[ks] = vh;
    }
    const float gb0 = GB[gcolb];
    const float gb1 = GB[gcolb + 16];
    const float cb  = CB[ccol];

    // ---------- init LDS state ----------
    for (int i = tid; i < 16 * HS; i += 512) hf[i] = 0.0f;
    for (int i = tid; i < 16 * BS; i += 512) hb[i] = 0;
    if (tid < 16) {
        lenbuf[tid]  = SL[b0 + tid];
        abuf[0][tid] = ATT[(size_t)(b0 + tid) * Tn];
    }

    // ---------- x A-frag register prefetch (per-lane slice, all waves same addrs) ----------
    // lane (q,lm) holds A[m=lm][k=ks*32+q*8+j] for j=0..7 as 8 f32 (2 float4).
    const float* xrow = X + (size_t)(b0 + lm) * Tn * Dn + q * 8;
    float4 xf0[4], xf1[4];
#pragma unroll
    for (int ks = 0; ks < 4; ++ks) {
        xf0[ks] = *(const float4*)(xrow + ks * 32);
        xf1[ks] = *(const float4*)(xrow + ks * 32 + 4);
    }
    __syncthreads();   // one-time: covers LDS init (vmcnt drain here is harmless)

    int len_i[4];
#pragma unroll
    for (int i = 0; i < 4; ++i) len_i[i] = lenbuf[q * 4 + i];

    // ---------- time loop ----------
    for (int t = 0; t < Tn; ++t) {
        const int cur = t & 1, nxt = cur ^ 1;

        // convert prefetched x regs -> bf16 A-frags (for this step)
        short8 ax[4];
#pragma unroll
        for (int ks = 0; ks < 4; ++ks) {
            short8 a;
            a[0] = f2bf(xf0[ks].x); a[1] = f2bf(xf0[ks].y);
            a[2] = f2bf(xf0[ks].z); a[3] = f2bf(xf0[ks].w);
            a[4] = f2bf(xf1[ks].x); a[5] = f2bf(xf1[ks].y);
            a[6] = f2bf(xf1[ks].z); a[7] = f2bf(xf1[ks].w);
            ax[ks] = a;
        }

        // issue x/att prefetch for t+1 (lands well before next-step convert)
        const int tp = (t + 1 < Tn) ? t + 1 : Tn - 1;
        const float* xnext = xrow + (size_t)tp * Dn;
#pragma unroll
        for (int ks = 0; ks < 4; ++ks) {
            xf0[ks] = *(const float4*)(xnext + ks * 32);
            xf1[ks] = *(const float4*)(xnext + ks * 32 + 4);
        }
        const float apre = (tid < 16) ? ATT[(size_t)(b0 + tid) * Tn + tp] : 0.0f;

        // h A-frags from LDS: A[m=lane&15][k=q*8+j]
        short8 ah[4];
#pragma unroll
        for (int ks = 0; ks < 4; ++ks)
            ah[ks] = *(const short8*)&hb[lm * BS + ks * 32 + q * 8];

        // gate: gi = [x,h] @ GK  (wave covers cols 32*wid .. +32)
        f32x4 g0 = {0.f, 0.f, 0.f, 0.f}, g1 = {0.f, 0.f, 0.f, 0.f};
#pragma unroll
        for (int ks = 0; ks < 4; ++ks) {
            g0 = __builtin_amdgcn_mfma_f32_16x16x32_bf16(ah[ks], fgh[0][ks], g0, 0, 0, 0);
            g1 = __builtin_amdgcn_mfma_f32_16x16x32_bf16(ah[ks], fgh[1][ks], g1, 0, 0, 0);
            g0 = __builtin_amdgcn_mfma_f32_16x16x32_bf16(ax[ks], fgx[0][ks], g0, 0, 0, 0);
            g1 = __builtin_amdgcn_mfma_f32_16x16x32_bf16(ax[ks], fgx[1][ks], g1, 0, 0, 0);
        }

        // activations (C/D layout: col=lane&15, row=q*4+i)
        if (wid < 4) {            // r cols 0..127
#pragma unroll
            for (int ns = 0; ns < 2; ++ns) {
                const int col = 32 * wid + 16 * ns + lm;
                const float bias = ns ? gb1 : gb0;
                const f32x4 gg = ns ? g1 : g0;
#pragma unroll
                for (int i = 0; i < 4; ++i) {
                    const int row = q * 4 + i;
                    const float r = sigmoidf_(gg[i] + bias);
                    rhb[row * BS + col] = f2bf(r * hf[row * HS + col]);
                }
            }
        } else {                  // u cols 128..255
#pragma unroll
            for (int ns = 0; ns < 2; ++ns) {
                const int cu = 32 * (wid - 4) + 16 * ns + lm;
                const float bias = ns ? gb1 : gb0;
                const f32x4 gg = ns ? g1 : g0;
#pragma unroll
                for (int i = 0; i < 4; ++i) {
                    const int row = q * 4 + i;
                    const float u = sigmoidf_(gg[i] + bias);
                    ub[row * HS + cu] = (1.0f - abuf[cur][row]) * u;
                }
            }
        }
        barrier_lds();

        // cand: c = tanh([x, r*h] @ CK + cb)  (wave covers cols 16*wid .. +16)
        f32x4 cc = {0.f, 0.f, 0.f, 0.f};
#pragma unroll
        for (int ks = 0; ks < 4; ++ks) {
            short8 arh = *(const short8*)&rhb[lm * BS + ks * 32 + q * 8];
            cc = __builtin_amdgcn_mfma_f32_16x16x32_bf16(arh, fch[ks], cc, 0, 0, 0);
            cc = __builtin_amdgcn_mfma_f32_16x16x32_bf16(ax[ks], fcx[ks], cc, 0, 0, 0);
        }

        // h update + output (each wave owns cand cols 16*wid..+16, all 16 rows)
#pragma unroll
        for (int i = 0; i < 4; ++i) {
            const int row = q * 4 + i;
            const float cv   = tanhf_(cc[i] + cb);
            const float up   = ub[row * HS + ccol];
            const float hold = hf[row * HS + ccol];
            const float hn   = up * hold + (1.0f - up) * cv;
            const bool valid = (t < len_i[i]);
            const float hnext = valid ? hn : hold;
            OUT[((size_t)(b0 + row) * Tn + t) * Dn + ccol] = valid ? hn : 0.0f;
            hf[row * HS + ccol] = hnext;
            hb[row * BS + ccol] = f2bf(hnext);
        }

        // stage prefetched att into next buffer
        if (tid < 16) abuf[nxt][tid] = apre;
        barrier_lds();
    }
}

extern "C" void kernel_launch(void* const* d_in, const int* in_sizes, int n_in,
                              void* d_out, int out_size, void* d_ws, size_t ws_size,
                              hipStream_t stream) {
    (void)in_sizes; (void)n_in; (void)d_ws; (void)ws_size; (void)out_size;
    const float* X   = (const float*)d_in[0];
    const float* ATT = (const float*)d_in[1];
    const float* GK  = (const float*)d_in[2];
    const float* GB  = (const float*)d_in[3];
    const float* CK  = (const float*)d_in[4];
    const float* CB  = (const float*)d_in[5];
    const int*   SL  = (const int*)d_in[6];
    float* OUT = (float*)d_out;

    augru_kernel<<<dim3(Bn / 16), dim3(512), 0, stream>>>(X, ATT, GK, GB, CK, CB, SL, OUT);
}

// Round 4
// 668.324 us; speedup vs baseline: 1.8536x; 1.8536x over previous
//
#include <hip/hip_runtime.h>
#include <hip/hip_bf16.h>

// AUGRU dynamic RNN:  B=1024 batch rows, T=512 steps, D=128.
// 64 blocks x 512 threads (8 waves); block owns 16 batch rows for all T.
// Base = verified 630us kernel (round-2: lgkm-only barriers). Round-4 edits
// are DEPENDENCY-GRAPH ONLY (work/structure identical):
//  * P1 gate MFMAs: 2x 8-deep accumulate chains -> 4x 4-deep independent
//    chains (g0a/g0b/g1a/g1b), merged with 2 vector adds.
//  * P2 cand MFMAs: 1x 8-deep chain -> 2x 4-deep (cc0 rh-part, cc1 x-part).
//    Halves the longest dependent-MFMA chain in the step.
//  * OUT / X-prefetch / ATT-prefetch addressing hoisted to running
//    pointers/offsets (removes per-step 64-bit addr chains from the
//    update path).
//  * launch_bounds (512,1): 64 blocks never co-reside per CU.

#define Bn 1024
#define Tn 512
#define Dn 128

typedef __attribute__((ext_vector_type(8))) short short8;   // 8 bf16 (4 VGPR)
typedef __attribute__((ext_vector_type(4))) short short4v;
typedef __attribute__((ext_vector_type(4))) float f32x4;

#define HS 132   // f32 LDS row stride (floats)  : 16x128 + pad
#define BS 136   // bf16 LDS row stride (shorts) : 272 B = 17*16B

__device__ __forceinline__ short f2bf(float f) {
    __hip_bfloat16 h = __float2bfloat16(f);   // RNE
    return __builtin_bit_cast(short, h);
}
__device__ __forceinline__ float sigmoidf_(float x) {
    float e = __expf(-x);
    return __builtin_amdgcn_rcpf(1.0f + e);
}
__device__ __forceinline__ float tanhf_(float x) {
    float e = __expf(-2.0f * x);
    return 2.0f * __builtin_amdgcn_rcpf(1.0f + e) - 1.0f;
}

// LDS-only barrier: order LDS ops across waves WITHOUT draining vmcnt
// (prefetch loads / OUT stores keep flying across the barrier).
__device__ __forceinline__ void barrier_lds() {
    __builtin_amdgcn_sched_barrier(0);
    asm volatile("s_waitcnt lgkmcnt(0)" ::: "memory");
    __builtin_amdgcn_s_barrier();
    __builtin_amdgcn_sched_barrier(0);
}

__launch_bounds__(512, 1)
__global__ void augru_kernel(const float* __restrict__ X,    // [B,T,D]
                             const float* __restrict__ ATT,  // [B,T,1]
                             const float* __restrict__ GK,   // [256,256]
                             const float* __restrict__ GB,   // [256]
                             const float* __restrict__ CK,   // [256,128]
                             const float* __restrict__ CB,   // [128]
                             const int*   __restrict__ SL,   // [B,1]
                             float* __restrict__ OUT) {      // [B,T,D]
    __shared__ short hb [16 * BS];      // h  (bf16 mirror, A-frag source)
    __shared__ short rhb[16 * BS];      // r*h (bf16, A-frag source)
    __shared__ short xb [2][16 * BS];   // x tile, double-buffered
    __shared__ float hf [16 * HS];      // master h (f32)
    __shared__ float ub [16 * HS];      // u' = (1-a)*u (f32)
    __shared__ float abuf[2][16];
    __shared__ int   lenbuf[16];

    const int tid  = threadIdx.x;
    const int wid  = tid >> 6;          // 0..7
    const int lane = tid & 63;
    const int lm   = lane & 15;         // MFMA m / n / col index
    const int q    = lane >> 4;         // quad
    const int b0   = blockIdx.x * 16;

    // ---------- preload weight B-frags (B[k][n]: n=lane&15, k=q*8+j) ----------
    short8 fgx[2][4], fgh[2][4], fcx[4], fch[4];
    const int gcolb = 32 * wid + lm;     // gate col base for this wave
    const int ccol  = 16 * wid + lm;     // cand col for this wave
#pragma unroll
    for (int ns = 0; ns < 2; ++ns) {
        const int col = gcolb + 16 * ns;
#pragma unroll
        for (int ks = 0; ks < 4; ++ks) {
            short8 vx, vh;
#pragma unroll
            for (int j = 0; j < 8; ++j) {
                const int k = ks * 32 + q * 8 + j;
                vx[j] = f2bf(GK[k * 256 + col]);           // x-part rows 0..127
                vh[j] = f2bf(GK[(128 + k) * 256 + col]);   // h-part rows 128..255
            }
            fgx[ns][ks] = vx; fgh[ns][ks] = vh;
        }
    }
#pragma unroll
    for (int ks = 0; ks < 4; ++ks) {
        short8 vx, vh;
#pragma unroll
        for (int j = 0; j < 8; ++j) {
            const int k = ks * 32 + q * 8 + j;
            vx[j] = f2bf(CK[k * 128 + ccol]);
            vh[j] = f2bf(CK[(128 + k) * 128 + ccol]);
        }
        fcx[ks] = vx; fch[ks] = vh;
    }
    const float gb0 = GB[gcolb];
    const float gb1 = GB[gcolb + 16];
    const float cb  = CB[ccol];

    // ---------- init LDS state ----------
    for (int i = tid; i < 16 * HS; i += 512) hf[i] = 0.0f;
    for (int i = tid; i < 16 * BS; i += 512) hb[i] = 0;
    if (tid < 16) {
        lenbuf[tid]  = SL[b0 + tid];
        abuf[0][tid] = ATT[(size_t)(b0 + tid) * Tn];
    }
    const int prow = tid >> 5;            // x staging: row 0..15
    const int pcol = (tid & 31) * 4;      // 4 consecutive floats
    {   // stage x for t=0
        float4 v = *(const float4*)(X + ((size_t)(b0 + prow) * Tn + 0) * Dn + pcol);
        short4v s; s[0] = f2bf(v.x); s[1] = f2bf(v.y); s[2] = f2bf(v.z); s[3] = f2bf(v.w);
        *(short4v*)&xb[0][prow * BS + pcol] = s;
    }
    __syncthreads();

    int len_i[4];
#pragma unroll
    for (int i = 0; i < 4; ++i) len_i[i] = lenbuf[q * 4 + i];

    // running pointers / offsets (hoisted addressing)
    const float* xptr = X + ((size_t)(b0 + prow) * Tn + 1) * Dn + pcol;     // row tp(0)=1
    const float* aptr = ATT + (size_t)(b0 + (tid & 15)) * Tn + 1;           // deref only if tid<16
    unsigned out_off[4];
#pragma unroll
    for (int i = 0; i < 4; ++i)
        out_off[i] = (unsigned)(((b0 + q * 4 + i) * Tn) * Dn + ccol);       // t=0

    // ---------- time loop ----------
    for (int t = 0; t < Tn; ++t) {
        const int cur = t & 1, nxt = cur ^ 1;

        // prefetch x/att for t+1 (consumed at bottom of this step)
        float4 xpre = *(const float4*)xptr;
        float  apre = 0.0f;
        if (tid < 16) apre = *aptr;
        const int adv = (t + 2 < Tn) ? 1 : 0;   // tp advances while t+2<=Tn-1
        xptr += adv * Dn;
        aptr += adv;

        // A-frags: A[m=lane&15][k=q*8+j]
        short8 ax[4], ah[4];
#pragma unroll
        for (int ks = 0; ks < 4; ++ks) {
            ax[ks] = *(const short8*)&xb[cur][lm * BS + ks * 32 + q * 8];
            ah[ks] = *(const short8*)&hb[lm * BS + ks * 32 + q * 8];
        }

        // gate: gi = [x,h] @ GK  (wave covers cols 32*wid .. +32)
        // 4 independent 4-deep chains instead of 2x 8-deep.
        f32x4 g0a = {0.f,0.f,0.f,0.f}, g0b = {0.f,0.f,0.f,0.f};
        f32x4 g1a = {0.f,0.f,0.f,0.f}, g1b = {0.f,0.f,0.f,0.f};
#pragma unroll
        for (int ks = 0; ks < 4; ++ks) {
            g0a = __builtin_amdgcn_mfma_f32_16x16x32_bf16(ah[ks], fgh[0][ks], g0a, 0, 0, 0);
            g1a = __builtin_amdgcn_mfma_f32_16x16x32_bf16(ah[ks], fgh[1][ks], g1a, 0, 0, 0);
            g0b = __builtin_amdgcn_mfma_f32_16x16x32_bf16(ax[ks], fgx[0][ks], g0b, 0, 0, 0);
            g1b = __builtin_amdgcn_mfma_f32_16x16x32_bf16(ax[ks], fgx[1][ks], g1b, 0, 0, 0);
        }
        const f32x4 g0 = g0a + g0b;
        const f32x4 g1 = g1a + g1b;

        // activations (C/D layout: col=lane&15, row=q*4+i)
        if (wid < 4) {            // r cols 0..127
#pragma unroll
            for (int ns = 0; ns < 2; ++ns) {
                const int col = 32 * wid + 16 * ns + lm;
                const float bias = ns ? gb1 : gb0;
                const f32x4 gg = ns ? g1 : g0;
#pragma unroll
                for (int i = 0; i < 4; ++i) {
                    const int row = q * 4 + i;
                    const float r = sigmoidf_(gg[i] + bias);
                    rhb[row * BS + col] = f2bf(r * hf[row * HS + col]);
                }
            }
        } else {                  // u cols 128..255
#pragma unroll
            for (int ns = 0; ns < 2; ++ns) {
                const int cu = 32 * (wid - 4) + 16 * ns + lm;
                const float bias = ns ? gb1 : gb0;
                const f32x4 gg = ns ? g1 : g0;
#pragma unroll
                for (int i = 0; i < 4; ++i) {
                    const int row = q * 4 + i;
                    const float u = sigmoidf_(gg[i] + bias);
                    ub[row * HS + cu] = (1.0f - abuf[cur][row]) * u;
                }
            }
        }
        barrier_lds();

        // cand: c = tanh([x, r*h] @ CK + cb)  (wave covers cols 16*wid .. +16)
        // 2 independent 4-deep chains instead of 1x 8-deep.
        f32x4 cc0 = {0.f,0.f,0.f,0.f}, cc1 = {0.f,0.f,0.f,0.f};
#pragma unroll
        for (int ks = 0; ks < 4; ++ks) {
            short8 arh = *(const short8*)&rhb[lm * BS + ks * 32 + q * 8];
            cc0 = __builtin_amdgcn_mfma_f32_16x16x32_bf16(arh, fch[ks], cc0, 0, 0, 0);
            cc1 = __builtin_amdgcn_mfma_f32_16x16x32_bf16(ax[ks], fcx[ks], cc1, 0, 0, 0);
        }
        const f32x4 cc = cc0 + cc1;

        // h update + output (each wave owns cand cols 16*wid..+16, all 16 rows)
#pragma unroll
        for (int i = 0; i < 4; ++i) {
            const int row = q * 4 + i;
            const float cv   = tanhf_(cc[i] + cb);
            const float up   = ub[row * HS + ccol];
            const float hold = hf[row * HS + ccol];
            const float hn   = up * hold + (1.0f - up) * cv;
            const bool valid = (t < len_i[i]);
            const float hnext = valid ? hn : hold;
            OUT[out_off[i]] = valid ? hn : 0.0f;
            out_off[i] += Dn;
            hf[row * HS + ccol] = hnext;
            hb[row * BS + ccol] = f2bf(hnext);
        }

        // stage prefetched x/att into next buffers
        {
            short4v s; s[0] = f2bf(xpre.x); s[1] = f2bf(xpre.y);
                       s[2] = f2bf(xpre.z); s[3] = f2bf(xpre.w);
            *(short4v*)&xb[nxt][prow * BS + pcol] = s;
            if (tid < 16) abuf[nxt][tid] = apre;
        }
        barrier_lds();
    }
}

extern "C" void kernel_launch(void* const* d_in, const int* in_sizes, int n_in,
                              void* d_out, int out_size, void* d_ws, size_t ws_size,
                              hipStream_t stream) {
    (void)in_sizes; (void)n_in; (void)d_ws; (void)ws_size; (void)out_size;
    const float* X   = (const float*)d_in[0];
    const float* ATT = (const float*)d_in[1];
    const float* GK  = (const float*)d_in[2];
    const float* GB  = (const float*)d_in[3];
    const float* CK  = (const float*)d_in[4];
    const float* CB  = (const float*)d_in[5];
    const int*   SL  = (const int*)d_in[6];
    float* OUT = (float*)d_out;

    augru_kernel<<<dim3(Bn / 16), dim3(512), 0, stream>>>(X, ATT, GK, GB, CK, CB, SL, OUT);
}

// Round 5
// 614.719 us; speedup vs baseline: 2.0152x; 1.0872x over previous
//
#include <hip/hip_runtime.h>
#include <hip/hip_bf16.h>

// AUGRU dynamic RNN:  B=1024 batch rows, T=512 steps, D=128.
// 64 blocks x 512 threads (8 waves); block owns 16 batch rows for all T.
// Base = verified 630us kernel (R2: lgkm-only barriers). Round-5 change:
// CROSS-STEP PIPELINING of the h-independent MFMAs. The x-projections
// (gate-x: 8 MFMAs, cand-x: 4 MFMAs per wave) do not depend on h, so step
// t computes step t+1's x-partials (ngx0/ngx1/ncx, from x(t+1) frags) as
// free-floating independent MFMAs, while step t's gate/cand accumulators
// START from the partials saved last step. Effects:
//  * act waits on a 4-deep MFMA chain (was 8-deep)
//  * tanh waits on a 4-deep chain (was 8-deep)
//  * 12 independent MFMAs per wave-step available to fill stalls
// Work count, LDS layout, act/update code, barrier structure: identical.
// x staging shifted one step earlier (xb[slot s&1] holds x(s); step t reads
// x(t+1) frags, stages x(t+2)). t-loop hand-unrolled x2 so the partial-sum
// register sets (A/B) are statically named (no scratch, rule #20).

#define Bn 1024
#define Tn 512
#define Dn 128

typedef __attribute__((ext_vector_type(8))) short short8;   // 8 bf16 (4 VGPR)
typedef __attribute__((ext_vector_type(4))) short short4v;
typedef __attribute__((ext_vector_type(4))) float f32x4;

#define HS 132   // f32 LDS row stride (floats)  : 16x128 + pad
#define BS 136   // bf16 LDS row stride (shorts) : 272 B = 17*16B

__device__ __forceinline__ short f2bf(float f) {
    __hip_bfloat16 h = __float2bfloat16(f);   // RNE
    return __builtin_bit_cast(short, h);
}
__device__ __forceinline__ float sigmoidf_(float x) {
    float e = __expf(-x);
    return __builtin_amdgcn_rcpf(1.0f + e);
}
__device__ __forceinline__ float tanhf_(float x) {
    float e = __expf(-2.0f * x);
    return 2.0f * __builtin_amdgcn_rcpf(1.0f + e) - 1.0f;
}

// LDS-only barrier: order LDS ops across waves WITHOUT draining vmcnt.
__device__ __forceinline__ void barrier_lds() {
    __builtin_amdgcn_sched_barrier(0);
    asm volatile("s_waitcnt lgkmcnt(0)" ::: "memory");
    __builtin_amdgcn_s_barrier();
    __builtin_amdgcn_sched_barrier(0);
}

#define MFMA_(a, b, c) __builtin_amdgcn_mfma_f32_16x16x32_bf16((a), (b), (c), 0, 0, 0)

__launch_bounds__(512, 2)
__global__ void augru_kernel(const float* __restrict__ X,    // [B,T,D]
                             const float* __restrict__ ATT,  // [B,T,1]
                             const float* __restrict__ GK,   // [256,256]
                             const float* __restrict__ GB,   // [256]
                             const float* __restrict__ CK,   // [256,128]
                             const float* __restrict__ CB,   // [128]
                             const int*   __restrict__ SL,   // [B,1]
                             float* __restrict__ OUT) {      // [B,T,D]
    __shared__ short hb [16 * BS];      // h  (bf16 mirror, A-frag source)
    __shared__ short rhb[16 * BS];      // r*h (bf16, A-frag source)
    __shared__ short xb [2][16 * BS];   // x tile; slot s&1 holds x(s)
    __shared__ float hf [16 * HS];      // master h (f32)
    __shared__ float ub [16 * HS];      // u' = (1-a)*u (f32)
    __shared__ float abuf[2][16];
    __shared__ int   lenbuf[16];

    const int tid  = threadIdx.x;
    const int wid  = tid >> 6;          // 0..7
    const int lane = tid & 63;
    const int lm   = lane & 15;         // MFMA m / n / col index
    const int q    = lane >> 4;         // quad
    const int b0   = blockIdx.x * 16;

    // ---------- preload weight B-frags (B[k][n]: n=lane&15, k=q*8+j) ----------
    short8 fgx[2][4], fgh[2][4], fcx[4], fch[4];
    const int gcolb = 32 * wid + lm;     // gate col base for this wave
    const int ccol  = 16 * wid + lm;     // cand col for this wave
#pragma unroll
    for (int ns = 0; ns < 2; ++ns) {
        const int col = gcolb + 16 * ns;
#pragma unroll
        for (int ks = 0; ks < 4; ++ks) {
            short8 vx, vh;
#pragma unroll
            for (int j = 0; j < 8; ++j) {
                const int k = ks * 32 + q * 8 + j;
                vx[j] = f2bf(GK[k * 256 + col]);           // x-part rows 0..127
                vh[j] = f2bf(GK[(128 + k) * 256 + col]);   // h-part rows 128..255
            }
            fgx[ns][ks] = vx; fgh[ns][ks] = vh;
        }
    }
#pragma unroll
    for (int ks = 0; ks < 4; ++ks) {
        short8 vx, vh;
#pragma unroll
        for (int j = 0; j < 8; ++j) {
            const int k = ks * 32 + q * 8 + j;
            vx[j] = f2bf(CK[k * 128 + ccol]);
            vh[j] = f2bf(CK[(128 + k) * 128 + ccol]);
        }
        fcx[ks] = vx; fch[ks] = vh;
    }
    const float gb0 = GB[gcolb];
    const float gb1 = GB[gcolb + 16];
    const float cb  = CB[ccol];

    // ---------- init LDS state ----------
    for (int i = tid; i < 16 * HS; i += 512) hf[i] = 0.0f;
    for (int i = tid; i < 16 * BS; i += 512) hb[i] = 0;
    if (tid < 16) {
        lenbuf[tid]  = SL[b0 + tid];
        abuf[0][tid] = ATT[(size_t)(b0 + tid) * Tn];
    }
    const int prow = tid >> 5;            // x staging: row 0..15
    const int pcol = (tid & 31) * 4;      // 4 consecutive floats
    {   // stage x(0) into xb[0]
        float4 v = *(const float4*)(X + ((size_t)(b0 + prow) * Tn + 0) * Dn + pcol);
        short4v s; s[0] = f2bf(v.x); s[1] = f2bf(v.y); s[2] = f2bf(v.z); s[3] = f2bf(v.w);
        *(short4v*)&xb[0][prow * BS + pcol] = s;
    }
    __syncthreads();

    int len_i[4];
#pragma unroll
    for (int i = 0; i < 4; ++i) len_i[i] = lenbuf[q * 4 + i];

    // ---------- prologue: x-partials for t=0; stage x(1) ----------
    f32x4 gxA0 = {0.f,0.f,0.f,0.f}, gxA1 = {0.f,0.f,0.f,0.f}, cxA = {0.f,0.f,0.f,0.f};
    f32x4 gxB0, gxB1, cxB;
    {
        short8 ax0[4];
#pragma unroll
        for (int ks = 0; ks < 4; ++ks)
            ax0[ks] = *(const short8*)&xb[0][lm * BS + ks * 32 + q * 8];
#pragma unroll
        for (int ks = 0; ks < 4; ++ks) {
            gxA0 = MFMA_(ax0[ks], fgx[0][ks], gxA0);
            gxA1 = MFMA_(ax0[ks], fgx[1][ks], gxA1);
            cxA  = MFMA_(ax0[ks], fcx[ks],  cxA);
        }
        float4 v = *(const float4*)(X + ((size_t)(b0 + prow) * Tn + 1) * Dn + pcol);
        short4v s; s[0] = f2bf(v.x); s[1] = f2bf(v.y); s[2] = f2bf(v.z); s[3] = f2bf(v.w);
        *(short4v*)&xb[1][prow * BS + pcol] = s;
    }
    __syncthreads();

    // One AUGRU step. Reads x-partials (GIN*/CIN) computed last step;
    // computes next step's partials into GOUT*/COUT from x(t+1) frags.
#define STEP_BODY(t, GIN0, GIN1, CIN, GOUT0, GOUT1, COUT)                         \
    {                                                                             \
        const int cur = (t) & 1, nxt = cur ^ 1;                                   \
        const int tp1 = ((t) + 1 < Tn) ? (t) + 1 : Tn - 1;                        \
        const int tp2 = ((t) + 2 < Tn) ? (t) + 2 : Tn - 1;                        \
        float4 xpre = *(const float4*)(X + ((size_t)(b0 + prow) * Tn + tp2) * Dn + pcol); \
        float  apre = (tid < 16) ? ATT[(size_t)(b0 + tid) * Tn + tp1] : 0.0f;     \
        /* A-frags: h(t) from hb, x(t+1) from xb[nxt] */                          \
        short8 axn[4], ah[4];                                                     \
        _Pragma("unroll")                                                         \
        for (int ks = 0; ks < 4; ++ks) {                                          \
            axn[ks] = *(const short8*)&xb[nxt][lm * BS + ks * 32 + q * 8];        \
            ah[ks]  = *(const short8*)&hb[lm * BS + ks * 32 + q * 8];             \
        }                                                                         \
        /* P1: gate = saved x-partial + h-part (4-deep); next x-partials float */ \
        f32x4 g0 = GIN0, g1 = GIN1;                                               \
        f32x4 ngx0 = {0.f,0.f,0.f,0.f}, ngx1 = {0.f,0.f,0.f,0.f};                 \
        f32x4 ncx  = {0.f,0.f,0.f,0.f};                                           \
        _Pragma("unroll")                                                         \
        for (int ks = 0; ks < 4; ++ks) {                                          \
            g0 = MFMA_(ah[ks], fgh[0][ks], g0);                                   \
            g1 = MFMA_(ah[ks], fgh[1][ks], g1);                                   \
        }                                                                         \
        _Pragma("unroll")                                                         \
        for (int ks = 0; ks < 4; ++ks) {                                          \
            ngx0 = MFMA_(axn[ks], fgx[0][ks], ngx0);                              \
            ngx1 = MFMA_(axn[ks], fgx[1][ks], ngx1);                              \
            ncx  = MFMA_(axn[ks], fcx[ks],  ncx);                                 \
        }                                                                         \
        /* activations (C/D layout: col=lane&15, row=q*4+i) */                    \
        if (wid < 4) {            /* r cols 0..127 */                             \
            _Pragma("unroll")                                                     \
            for (int ns = 0; ns < 2; ++ns) {                                      \
                const int col = 32 * wid + 16 * ns + lm;                          \
                const float bias = ns ? gb1 : gb0;                                \
                const f32x4 gg = ns ? g1 : g0;                                    \
                _Pragma("unroll")                                                 \
                for (int i = 0; i < 4; ++i) {                                     \
                    const int row = q * 4 + i;                                    \
                    const float r = sigmoidf_(gg[i] + bias);                      \
                    rhb[row * BS + col] = f2bf(r * hf[row * HS + col]);           \
                }                                                                 \
            }                                                                     \
        } else {                  /* u cols 128..255 */                           \
            _Pragma("unroll")                                                     \
            for (int ns = 0; ns < 2; ++ns) {                                      \
                const int cu = 32 * (wid - 4) + 16 * ns + lm;                     \
                const float bias = ns ? gb1 : gb0;                                \
                const f32x4 gg = ns ? g1 : g0;                                    \
                _Pragma("unroll")                                                 \
                for (int i = 0; i < 4; ++i) {                                     \
                    const int row = q * 4 + i;                                    \
                    const float u = sigmoidf_(gg[i] + bias);                      \
                    ub[row * HS + cu] = (1.0f - abuf[cur][row]) * u;              \
                }                                                                 \
            }                                                                     \
        }                                                                         \
        barrier_lds();                                                            \
        /* P2: cand = saved x-partial + rh-part (4-deep) */                       \
        f32x4 cc = CIN;                                                           \
        _Pragma("unroll")                                                         \
        for (int ks = 0; ks < 4; ++ks) {                                          \
            short8 arh = *(const short8*)&rhb[lm * BS + ks * 32 + q * 8];         \
            cc = MFMA_(arh, fch[ks], cc);                                         \
        }                                                                         \
        /* h update + output */                                                   \
        _Pragma("unroll")                                                         \
        for (int i = 0; i < 4; ++i) {                                             \
            const int row = q * 4 + i;                                            \
            const float cv   = tanhf_(cc[i] + cb);                                \
            const float up   = ub[row * HS + ccol];                               \
            const float hold = hf[row * HS + ccol];                               \
            const float hn   = up * hold + (1.0f - up) * cv;                      \
            const bool valid = ((t) < len_i[i]);                                  \
            const float hnext = valid ? hn : hold;                                \
            OUT[((size_t)(b0 + row) * Tn + (t)) * Dn + ccol] = valid ? hn : 0.0f; \
            hf[row * HS + ccol] = hnext;                                          \
            hb[row * BS + ccol] = f2bf(hnext);                                    \
        }                                                                         \
        /* stage x(t+2) into xb[cur]; a(t+1) into abuf[nxt] */                    \
        {                                                                         \
            short4v s; s[0] = f2bf(xpre.x); s[1] = f2bf(xpre.y);                  \
                       s[2] = f2bf(xpre.z); s[3] = f2bf(xpre.w);                  \
            *(short4v*)&xb[cur][prow * BS + pcol] = s;                            \
            if (tid < 16) abuf[nxt][tid] = apre;                                  \
        }                                                                         \
        barrier_lds();                                                            \
        GOUT0 = ngx0; GOUT1 = ngx1; COUT = ncx;                                   \
    }

    // ---------- time loop (unrolled x2: static A/B partial-sum sets) ----------
    for (int t = 0; t < Tn; t += 2) {
        STEP_BODY(t,     gxA0, gxA1, cxA, gxB0, gxB1, cxB)
        STEP_BODY(t + 1, gxB0, gxB1, cxB, gxA0, gxA1, cxA)
    }
#undef STEP_BODY
}

extern "C" void kernel_launch(void* const* d_in, const int* in_sizes, int n_in,
                              void* d_out, int out_size, void* d_ws, size_t ws_size,
                              hipStream_t stream) {
    (void)in_sizes; (void)n_in; (void)d_ws; (void)ws_size; (void)out_size;
    const float* X   = (const float*)d_in[0];
    const float* ATT = (const float*)d_in[1];
    const float* GK  = (const float*)d_in[2];
    const float* GB  = (const float*)d_in[3];
    const float* CK  = (const float*)d_in[4];
    const float* CB  = (const float*)d_in[5];
    const int*   SL  = (const int*)d_in[6];
    float* OUT = (float*)d_out;

    augru_kernel<<<dim3(Bn / 16), dim3(512), 0, stream>>>(X, ATT, GK, GB, CK, CB, SL, OUT);
}

// Round 6
// 587.569 us; speedup vs baseline: 2.1084x; 1.0462x over previous
//
#include <hip/hip_runtime.h>
#include <hip/hip_bf16.h>

// AUGRU dynamic RNN:  B=1024 batch rows, T=512 steps, D=128.
// 64 blocks x 512 threads (8 waves); block owns 16 batch rows for all T.
// Base = R5 (614.7us): cross-step pipelined x-partials, lgkm-only barriers.
// Round-6 change: VALU-pipe reduction (structure/mappings/barriers identical).
//  * All hot-loop f32->bf16 conversions (rhb 8, hb 4, x-stage 4 per thread)
//    via v_cvt_pk_bf16_f32 (1 instr / 2 conversions, HW RNE) instead of
//    hipcc's ~5-instr software-RNE sequence. Inline asm, NO fences.
//  * Gate/cand biases folded into exp2 argument:
//    sigmoid(g+b) = rcp(1 + exp2(fma(g, -log2e, b*-log2e)));
//    tanh(c+cb)   = 2*rcp(1 + exp2(fma(c, -2log2e, cb*-2log2e))) - 1.
//  * (1-a) hoisted to 4 values/lane; hn = fma(up, hold-cv, cv).
// VALU is the measured dominant pipe (47% of active-SIMD cycles); f2bf was
// its largest block (~100 instr/thread/step).

#define Bn 1024
#define Tn 512
#define Dn 128

typedef __attribute__((ext_vector_type(8))) short short8;   // 8 bf16 (4 VGPR)
typedef __attribute__((ext_vector_type(4))) short short4v;
typedef __attribute__((ext_vector_type(4))) float f32x4;

#define HS 132   // f32 LDS row stride (floats)  : 16x128 + pad
#define BS 136   // bf16 LDS row stride (shorts) : 272 B = 17*16B

#define NL2E  (-1.4426950408889634f)   // -log2(e)
#define N2L2E (-2.8853900817779268f)   // -2*log2(e)

__device__ __forceinline__ short f2bf(float f) {            // cold paths only
    __hip_bfloat16 h = __float2bfloat16(f);   // RNE
    return __builtin_bit_cast(short, h);
}
// v_cvt_pk_bf16_f32: lo16 = bf16(a), hi16 = bf16(b). HW RNE. No builtin on
// gfx950 -> inline asm, pure register constraints (scheduler stays free).
__device__ __forceinline__ unsigned cvt_pk_bf16(float a, float b) {
    unsigned r;
    asm("v_cvt_pk_bf16_f32 %0, %1, %2" : "=v"(r) : "v"(a), "v"(b));
    return r;
}

// LDS-only barrier: order LDS ops across waves WITHOUT draining vmcnt.
__device__ __forceinline__ void barrier_lds() {
    __builtin_amdgcn_sched_barrier(0);
    asm volatile("s_waitcnt lgkmcnt(0)" ::: "memory");
    __builtin_amdgcn_s_barrier();
    __builtin_amdgcn_sched_barrier(0);
}

#define MFMA_(a, b, c) __builtin_amdgcn_mfma_f32_16x16x32_bf16((a), (b), (c), 0, 0, 0)

__launch_bounds__(512, 2)
__global__ void augru_kernel(const float* __restrict__ X,    // [B,T,D]
                             const float* __restrict__ ATT,  // [B,T,1]
                             const float* __restrict__ GK,   // [256,256]
                             const float* __restrict__ GB,   // [256]
                             const float* __restrict__ CK,   // [256,128]
                             const float* __restrict__ CB,   // [128]
                             const int*   __restrict__ SL,   // [B,1]
                             float* __restrict__ OUT) {      // [B,T,D]
    __shared__ short hb [16 * BS];      // h  (bf16 mirror, A-frag source)
    __shared__ short rhb[16 * BS];      // r*h (bf16, A-frag source)
    __shared__ short xb [2][16 * BS];   // x tile; slot s&1 holds x(s)
    __shared__ float hf [16 * HS];      // master h (f32)
    __shared__ float ub [16 * HS];      // u' = (1-a)*u (f32)
    __shared__ float abuf[2][16];
    __shared__ int   lenbuf[16];

    const int tid  = threadIdx.x;
    const int wid  = tid >> 6;          // 0..7
    const int lane = tid & 63;
    const int lm   = lane & 15;         // MFMA m / n / col index
    const int q    = lane >> 4;         // quad
    const int b0   = blockIdx.x * 16;

    // ---------- preload weight B-frags (B[k][n]: n=lane&15, k=q*8+j) ----------
    short8 fgx[2][4], fgh[2][4], fcx[4], fch[4];
    const int gcolb = 32 * wid + lm;     // gate col base for this wave
    const int ccol  = 16 * wid + lm;     // cand col for this wave
#pragma unroll
    for (int ns = 0; ns < 2; ++ns) {
        const int col = gcolb + 16 * ns;
#pragma unroll
        for (int ks = 0; ks < 4; ++ks) {
            short8 vx, vh;
#pragma unroll
            for (int j = 0; j < 8; ++j) {
                const int k = ks * 32 + q * 8 + j;
                vx[j] = f2bf(GK[k * 256 + col]);           // x-part rows 0..127
                vh[j] = f2bf(GK[(128 + k) * 256 + col]);   // h-part rows 128..255
            }
            fgx[ns][ks] = vx; fgh[ns][ks] = vh;
        }
    }
#pragma unroll
    for (int ks = 0; ks < 4; ++ks) {
        short8 vx, vh;
#pragma unroll
        for (int j = 0; j < 8; ++j) {
            const int k = ks * 32 + q * 8 + j;
            vx[j] = f2bf(CK[k * 128 + ccol]);
            vh[j] = f2bf(CK[(128 + k) * 128 + ccol]);
        }
        fcx[ks] = vx; fch[ks] = vh;
    }
    // biases pre-folded into exp2 argument
    const float pb0 = GB[gcolb]      * NL2E;
    const float pb1 = GB[gcolb + 16] * NL2E;
    const float cbp = CB[ccol]       * N2L2E;

    // ---------- init LDS state ----------
    for (int i = tid; i < 16 * HS; i += 512) hf[i] = 0.0f;
    for (int i = tid; i < 16 * BS; i += 512) hb[i] = 0;
    if (tid < 16) {
        lenbuf[tid]  = SL[b0 + tid];
        abuf[0][tid] = ATT[(size_t)(b0 + tid) * Tn];
    }
    const int prow = tid >> 5;            // x staging: row 0..15
    const int pcol = (tid & 31) * 4;      // 4 consecutive floats
    {   // stage x(0) into xb[0]
        float4 v = *(const float4*)(X + ((size_t)(b0 + prow) * Tn + 0) * Dn + pcol);
        short4v s; s[0] = f2bf(v.x); s[1] = f2bf(v.y); s[2] = f2bf(v.z); s[3] = f2bf(v.w);
        *(short4v*)&xb[0][prow * BS + pcol] = s;
    }
    __syncthreads();

    int len_i[4];
#pragma unroll
    for (int i = 0; i < 4; ++i) len_i[i] = lenbuf[q * 4 + i];

    // ---------- prologue: x-partials for t=0; stage x(1) ----------
    f32x4 gxA0 = {0.f,0.f,0.f,0.f}, gxA1 = {0.f,0.f,0.f,0.f}, cxA = {0.f,0.f,0.f,0.f};
    f32x4 gxB0, gxB1, cxB;
    {
        short8 ax0[4];
#pragma unroll
        for (int ks = 0; ks < 4; ++ks)
            ax0[ks] = *(const short8*)&xb[0][lm * BS + ks * 32 + q * 8];
#pragma unroll
        for (int ks = 0; ks < 4; ++ks) {
            gxA0 = MFMA_(ax0[ks], fgx[0][ks], gxA0);
            gxA1 = MFMA_(ax0[ks], fgx[1][ks], gxA1);
            cxA  = MFMA_(ax0[ks], fcx[ks],  cxA);
        }
        float4 v = *(const float4*)(X + ((size_t)(b0 + prow) * Tn + 1) * Dn + pcol);
        short4v s; s[0] = f2bf(v.x); s[1] = f2bf(v.y); s[2] = f2bf(v.z); s[3] = f2bf(v.w);
        *(short4v*)&xb[1][prow * BS + pcol] = s;
    }
    __syncthreads();

    // One AUGRU step. Reads x-partials (GIN*/CIN) computed last step;
    // computes next step's partials into GOUT*/COUT from x(t+1) frags.
#define STEP_BODY(t, GIN0, GIN1, CIN, GOUT0, GOUT1, COUT)                         \
    {                                                                             \
        const int cur = (t) & 1, nxt = cur ^ 1;                                   \
        const int tp1 = ((t) + 1 < Tn) ? (t) + 1 : Tn - 1;                        \
        const int tp2 = ((t) + 2 < Tn) ? (t) + 2 : Tn - 1;                        \
        float4 xpre = *(const float4*)(X + ((size_t)(b0 + prow) * Tn + tp2) * Dn + pcol); \
        float  apre = (tid < 16) ? ATT[(size_t)(b0 + tid) * Tn + tp1] : 0.0f;     \
        /* A-frags: h(t) from hb, x(t+1) from xb[nxt] */                          \
        short8 axn[4], ah[4];                                                     \
        _Pragma("unroll")                                                         \
        for (int ks = 0; ks < 4; ++ks) {                                          \
            axn[ks] = *(const short8*)&xb[nxt][lm * BS + ks * 32 + q * 8];        \
            ah[ks]  = *(const short8*)&hb[lm * BS + ks * 32 + q * 8];             \
        }                                                                         \
        /* P1: gate = saved x-partial + h-part (4-deep); next x-partials float */ \
        f32x4 g0 = GIN0, g1 = GIN1;                                               \
        f32x4 ngx0 = {0.f,0.f,0.f,0.f}, ngx1 = {0.f,0.f,0.f,0.f};                 \
        f32x4 ncx  = {0.f,0.f,0.f,0.f};                                           \
        _Pragma("unroll")                                                         \
        for (int ks = 0; ks < 4; ++ks) {                                          \
            g0 = MFMA_(ah[ks], fgh[0][ks], g0);                                   \
            g1 = MFMA_(ah[ks], fgh[1][ks], g1);                                   \
        }                                                                         \
        _Pragma("unroll")                                                         \
        for (int ks = 0; ks < 4; ++ks) {                                          \
            ngx0 = MFMA_(axn[ks], fgx[0][ks], ngx0);                              \
            ngx1 = MFMA_(axn[ks], fgx[1][ks], ngx1);                              \
            ncx  = MFMA_(axn[ks], fcx[ks],  ncx);                                 \
        }                                                                         \
        /* activations (C/D layout: col=lane&15, row=q*4+i) */                    \
        if (wid < 4) {            /* r cols: col0=32w+lm, col1=col0+16 */         \
            const int col0 = 32 * wid + lm;                                       \
            _Pragma("unroll")                                                     \
            for (int i = 0; i < 4; ++i) {                                         \
                const int row = q * 4 + i;                                        \
                const float e0 = __builtin_amdgcn_exp2f(fmaf(g0[i], NL2E, pb0));  \
                const float e1 = __builtin_amdgcn_exp2f(fmaf(g1[i], NL2E, pb1));  \
                const float rh0 = __builtin_amdgcn_rcpf(1.0f + e0) * hf[row * HS + col0];      \
                const float rh1 = __builtin_amdgcn_rcpf(1.0f + e1) * hf[row * HS + col0 + 16]; \
                const unsigned p = cvt_pk_bf16(rh0, rh1);                         \
                rhb[row * BS + col0]      = (short)p;                             \
                rhb[row * BS + col0 + 16] = (short)(p >> 16);                     \
            }                                                                     \
        } else {                  /* u cols 128..255 */                           \
            const int cu0 = 32 * (wid - 4) + lm;                                  \
            float am[4];                                                          \
            _Pragma("unroll")                                                     \
            for (int i = 0; i < 4; ++i) am[i] = 1.0f - abuf[cur][q * 4 + i];      \
            _Pragma("unroll")                                                     \
            for (int i = 0; i < 4; ++i) {                                         \
                const int row = q * 4 + i;                                        \
                const float e0 = __builtin_amdgcn_exp2f(fmaf(g0[i], NL2E, pb0));  \
                const float e1 = __builtin_amdgcn_exp2f(fmaf(g1[i], NL2E, pb1));  \
                ub[row * HS + cu0]      = am[i] * __builtin_amdgcn_rcpf(1.0f + e0); \
                ub[row * HS + cu0 + 16] = am[i] * __builtin_amdgcn_rcpf(1.0f + e1); \
            }                                                                     \
        }                                                                         \
        barrier_lds();                                                            \
        /* P2: cand = saved x-partial + rh-part (4-deep) */                       \
        f32x4 cc = CIN;                                                           \
        _Pragma("unroll")                                                         \
        for (int ks = 0; ks < 4; ++ks) {                                          \
            short8 arh = *(const short8*)&rhb[lm * BS + ks * 32 + q * 8];         \
            cc = MFMA_(arh, fch[ks], cc);                                         \
        }                                                                         \
        /* h update + output */                                                   \
        float hxv[4];                                                             \
        _Pragma("unroll")                                                         \
        for (int i = 0; i < 4; ++i) {                                             \
            const int row = q * 4 + i;                                            \
            const float e  = __builtin_amdgcn_exp2f(fmaf(cc[i], N2L2E, cbp));     \
            const float cv = fmaf(2.0f, __builtin_amdgcn_rcpf(1.0f + e), -1.0f);  \
            const float up   = ub[row * HS + ccol];                               \
            const float hold = hf[row * HS + ccol];                               \
            const float hn   = fmaf(up, hold - cv, cv);                           \
            const bool valid = ((t) < len_i[i]);                                  \
            const float hnext = valid ? hn : hold;                                \
            OUT[((size_t)(b0 + row) * Tn + (t)) * Dn + ccol] = valid ? hn : 0.0f; \
            hf[row * HS + ccol] = hnext;                                          \
            hxv[i] = hnext;                                                       \
        }                                                                         \
        {                                                                         \
            const unsigned pA = cvt_pk_bf16(hxv[0], hxv[1]);                      \
            const unsigned pB = cvt_pk_bf16(hxv[2], hxv[3]);                      \
            hb[(q * 4 + 0) * BS + ccol] = (short)pA;                              \
            hb[(q * 4 + 1) * BS + ccol] = (short)(pA >> 16);                      \
            hb[(q * 4 + 2) * BS + ccol] = (short)pB;                              \
            hb[(q * 4 + 3) * BS + ccol] = (short)(pB >> 16);                      \
        }                                                                         \
        /* stage x(t+2) into xb[cur]; a(t+1) into abuf[nxt] */                    \
        {                                                                         \
            uint2 pp;                                                             \
            pp.x = cvt_pk_bf16(xpre.x, xpre.y);                                   \
            pp.y = cvt_pk_bf16(xpre.z, xpre.w);                                   \
            *(uint2*)&xb[cur][prow * BS + pcol] = pp;                             \
            if (tid < 16) abuf[nxt][tid] = apre;                                  \
        }                                                                         \
        barrier_lds();                                                            \
        GOUT0 = ngx0; GOUT1 = ngx1; COUT = ncx;                                   \
    }

    // ---------- time loop (unrolled x2: static A/B partial-sum sets) ----------
    for (int t = 0; t < Tn; t += 2) {
        STEP_BODY(t,     gxA0, gxA1, cxA, gxB0, gxB1, cxB)
        STEP_BODY(t + 1, gxB0, gxB1, cxB, gxA0, gxA1, cxA)
    }
#undef STEP_BODY
}

extern "C" void kernel_launch(void* const* d_in, const int* in_sizes, int n_in,
                              void* d_out, int out_size, void* d_ws, size_t ws_size,
                              hipStream_t stream) {
    (void)in_sizes; (void)n_in; (void)d_ws; (void)ws_size; (void)out_size;
    const float* X   = (const float*)d_in[0];
    const float* ATT = (const float*)d_in[1];
    const float* GK  = (const float*)d_in[2];
    const float* GB  = (const float*)d_in[3];
    const float* CK  = (const float*)d_in[4];
    const float* CB  = (const float*)d_in[5];
    const int*   SL  = (const int*)d_in[6];
    float* OUT = (float*)d_out;

    augru_kernel<<<dim3(Bn / 16), dim3(512), 0, stream>>>(X, ATT, GK, GB, CK, CB, SL, OUT);
}